// Round 2
// 666.656 us; speedup vs baseline: 1.2917x; 1.2917x over previous
//
#include <hip/hip_runtime.h>

// ---- static problem structure -------------------------------------------
// Inputs (dict order!): A0, B0, A1, B1, A2, B2, A3, B3 : [4096, 2l+1, 16] f32.
// Packed per-batch layout (256 floats): row offsets loff = {0,16,64,144},
// element (l, m_i, p) at loff[l] + m_i*16 + p.
// Output per batch: for l=0..3, for M, for pair (l1,l2) valid, 256-elt tile
// (p*16+q). Tile base = base[l] + (M*npairs[l] + pair)*256.
// base = {0,1024,7936,22016}, npairs = {4,9,11,10}. Total 39936 f32/batch.
#define NTILES 156
#define NTERMS 478
#define PB_OUT 39936

// ---- compile-time Clebsch-Gordan table ----------------------------------
// Input-independent; evaluated entirely by the host compiler into a
// constant blob (no device-side table build, no runtime init).

constexpr double cfact(int n){ double f=1.0; for(int i=2;i<=n;++i) f*=(double)i; return f; }

constexpr double csqrt(double x){
  double g = (x > 1.0) ? x : 1.0;
  for (int i = 0; i < 32; ++i) g = 0.5*(g + x/g);   // Newton, converged long before 32
  return g;
}

constexpr double cg_coef(int j1,int m1,int j2,int m2,int j,int m){
  if (m1+m2 != m) return 0.0;
  double pref = csqrt((2.0*j+1.0)*cfact(j+j1-j2)*cfact(j-j1+j2)*cfact(j1+j2-j)/cfact(j1+j2+j+1));
  pref *= csqrt(cfact(j+m)*cfact(j-m)*cfact(j1+m1)*cfact(j1-m1)*cfact(j2+m2)*cfact(j2-m2));
  double s = 0.0;
  for (int k = 0; k <= j1+j2-j; ++k){
    int d2=j1+j2-j-k, d3=j1-m1-k, d4=j2+m2-k, d5=j-j2+m1+k, d6=j-j1-m2+k;
    if (d2<0||d3<0||d4<0||d5<0||d6<0) continue;
    double denom = cfact(k)*cfact(d2)*cfact(d3)*cfact(d4)*cfact(d5)*cfact(d6);
    s += ((k&1) ? -1.0 : 1.0)/denom;
  }
  return pref*s;
}

struct Tables {
  int   tiles[NTILES];   // out_off | (term_start<<16) | (count<<26)
  int   tpack[NTERMS];   // a_off | (b_off<<8)   (offsets into packed 256-f LDS)
  float tcg[NTERMS];     // CG coefficient
};

constexpr Tables build_tables(){
  Tables t{};
  const int loff[4]   = {0,16,64,144};
  const int base[4]   = {0,1024,7936,22016};
  const int npairs[4] = {4,9,11,10};
  int tile_i = 0, term_i = 0;
  for (int l = 0; l <= 3; ++l){
    int pair_i = 0;
    for (int l1 = 0; l1 <= 3; ++l1){
      for (int l2 = 0; l2 <= 3; ++l2){
        int dl = l1 - l2; if (dl < 0) dl = -dl;
        if (!(dl <= l && l <= l1 + l2)) continue;
        for (int Mi = 0; Mi < 2*l + 1; ++Mi){
          int M = Mi - l;
          int m1lo = (-l1 > M - l2) ? -l1 : M - l2;
          int m1hi = ( l1 < M + l2) ?  l1 : M + l2;
          int cnt  = m1hi - m1lo + 1;
          int ooff = base[l] + (Mi*npairs[l] + pair_i)*256;
          t.tiles[tile_i] = ooff | (term_i << 16) | (cnt << 26);
          for (int m1 = m1lo; m1 <= m1hi; ++m1){
            int m2 = M - m1;
            t.tpack[term_i] = (loff[l1] + (m1 + l1)*16) | ((loff[l2] + (m2 + l2)*16) << 8);
            t.tcg[term_i]   = (float)cg_coef(l1, m1, l2, m2, l, M);
            ++term_i;
          }
          ++tile_i;
        }
        ++pair_i;
      }
    }
  }
  return t;
}

// Host-side constexpr object first (guaranteed compile-time evaluation),
// then a plain constant-copy into __constant__ address space.
static constexpr Tables k_tab = build_tables();
__constant__ Tables g_tab = k_tab;

// ---- main kernel ---------------------------------------------------------
// Per block (one batch element): stage packed A/B (256 f each) into LDS,
// then 4 waves sweep the 156 output tiles. All table metadata is read via
// wave-uniform indices -> scalar-cache s_loads (no LDS staging of tables).
__global__ __launch_bounds__(256) void cg_main(
    const float* __restrict__ A0, const float* __restrict__ A1,
    const float* __restrict__ A2, const float* __restrict__ A3,
    const float* __restrict__ B0, const float* __restrict__ B1,
    const float* __restrict__ B2, const float* __restrict__ B3,
    float* __restrict__ out)
{
  __shared__ __align__(16) float Ash[256];
  __shared__ __align__(16) float Bsh[256];

  const int tid = threadIdx.x;
  const int b   = blockIdx.x;

  // stage packed A/B: 128 threads x float4 (row starts are 16-float aligned,
  // so every float4 lies inside one source array)
  if (tid < 128){
    const bool isA = tid < 64;
    const int  i4  = (tid & 63) << 2;     // packed float index 0,4,...,252
    const float* src; int off;
    if      (i4 < 16)  { src = isA ? A0 : B0; off = b*16  + i4;       }
    else if (i4 < 64)  { src = isA ? A1 : B1; off = b*48  + i4 - 16;  }
    else if (i4 < 144) { src = isA ? A2 : B2; off = b*80  + i4 - 64;  }
    else               { src = isA ? A3 : B3; off = b*112 + i4 - 144; }
    const float4 v = *(const float4*)&src[off];
    float* dst = isA ? Ash : Bsh;
    *(float4*)&dst[i4] = v;
  }
  __syncthreads();

  const int lane = tid & 63;
  const int wv   = __builtin_amdgcn_readfirstlane(tid >> 6); // wave id 0..3 (force SGPR)
  const int p    = lane >> 2;          // 0..15
  const int q0   = (lane & 3) << 2;    // 0,4,8,12
  float* outb = out + (size_t)b * PB_OUT;

  // 156 tiles, 4 waves -> 39 groups; each thread emits one float4 per tile
  for (int tg = 0; tg < NTILES; tg += 4){
    const int meta = g_tab.tiles[tg + wv];     // s_load (uniform)
    const int ooff = meta & 0xFFFF;
    const int ts   = (meta >> 16) & 0x3FF;
    const int tc   = meta >> 26;
    float4 acc = {0.f, 0.f, 0.f, 0.f};
    for (int i = 0; i < tc; ++i){
      const int   pk = g_tab.tpack[ts + i];    // s_load (uniform)
      const float cg = g_tab.tcg[ts + i];      // s_load (uniform)
      const float a  = Ash[(pk & 0xFF) + p];               // ds_read_b32, broadcast x4
      const float4 bq = *(const float4*)&Bsh[(pk >> 8) + q0]; // ds_read_b128, conflict-free
      const float ca = cg * a;
      acc.x = fmaf(ca, bq.x, acc.x);
      acc.y = fmaf(ca, bq.y, acc.y);
      acc.z = fmaf(ca, bq.z, acc.z);
      acc.w = fmaf(ca, bq.w, acc.w);
    }
    *(float4*)&outb[ooff + (lane << 2)] = acc;  // 1 KB/wave, fully coalesced
  }
}

extern "C" void kernel_launch(void* const* d_in, const int* in_sizes, int n_in,
                              void* d_out, int out_size, void* d_ws, size_t ws_size,
                              hipStream_t stream)
{
  // setup_inputs() dict order is INTERLEAVED: A0,B0,A1,B1,A2,B2,A3,B3
  const float* A0 = (const float*)d_in[0];
  const float* B0 = (const float*)d_in[1];
  const float* A1 = (const float*)d_in[2];
  const float* B1 = (const float*)d_in[3];
  const float* A2 = (const float*)d_in[4];
  const float* B2 = (const float*)d_in[5];
  const float* A3 = (const float*)d_in[6];
  const float* B3 = (const float*)d_in[7];
  float* out = (float*)d_out;

  // A0 is [batch,1,16]; in_sizes are element counts (proven by the round-0
  // passing run: in_sizes[0]/16 == 4096).
  const int batch = in_sizes[0] / 16;

  cg_main<<<batch, 256, 0, stream>>>(A0, A1, A2, A3, B0, B1, B2, B3, out);
}